// Round 8
// baseline (336.510 us; speedup 1.0000x reference)
//
#include <hip/hip_runtime.h>
#include <stdint.h>

typedef unsigned long long u64;
typedef unsigned int u32;
typedef float f32x4 __attribute__((ext_vector_type(4)));

#define T_STEPS 100
#define NNEUR 256
#define NBF 2048                 // B*F = 32*64
#define NELEM (NBF * NNEUR)      // 524288 per time step
#define T_PAIR 2                 // t-steps per bits block

// ---- Threefry-2x32, 20 rounds, exactly as jax/_src/prng.py ----
__device__ __forceinline__ void tf2x32(u32 k0, u32 k1, u32& x0, u32& x1) {
  u32 k2 = k0 ^ k1 ^ 0x1BD11BDAu;
  x0 += k0; x1 += k1;
#define TFR(r) { x0 += x1; x1 = (x1 << (r)) | (x1 >> (32 - (r))); x1 ^= x0; }
  TFR(13) TFR(15) TFR(26) TFR(6)
  x0 += k1; x1 += k2 + 1u;
  TFR(17) TFR(29) TFR(16) TFR(24)
  x0 += k2; x1 += k0 + 2u;
  TFR(13) TFR(15) TFR(26) TFR(6)
  x0 += k0; x1 += k1 + 3u;
  TFR(17) TFR(29) TFR(16) TFR(24)
  x0 += k1; x1 += k2 + 4u;
  TFR(13) TFR(15) TFR(26) TFR(6)
  x0 += k2; x1 += k0 + 5u;
#undef TFR
}

__device__ __forceinline__ u32 rotl32(u32 x, int r) {
  return __builtin_amdgcn_alignbit(x, x, 32 - r);   // v_alignbit_b32
}

// thr9[i] = ceil(p_i * 2^23) << 9 : integer threshold for (x0^x1) < thr9
// (exact: (m>>9) < T  <=>  m < T<<9; T <= ceil(0.1*2^23) so no overflow)
// Block 0 also zeroes the occ accumulator (replaces the memset node).
__global__ void __launch_bounds__(256) kern_p(
    const float* __restrict__ x, const float* __restrict__ c,
    const float* __restrict__ w, const float* __restrict__ a,
    u32* __restrict__ thr9, u32* __restrict__ occ32) {
  int idx = blockIdx.x * 256 + threadIdx.x;
  int n = idx & 255, bf = idx >> 8;
  float d = x[bf] - c[n];
  float denom = (2.0f * w[n]) * w[n];
  float q = -(d * d) / denom;
  float e = (float)exp((double)q);
  float p = (e * a[n]) * 0.1f;
  thr9[idx] = ((u32)ceilf(p * 8388608.0f)) << 9;
  if (blockIdx.x == 0 && threadIdx.x < 200) {
    ((uint4*)occ32)[threadIdx.x] = make_uint4(0u, 0u, 0u, 0u);
  }
}

// Stage A: thread owns (bf, 16 neurons) x 2 t-steps. Two threefry chains
// (k and k+8) interleaved in lockstep for guaranteed ILP=2; occ OR-reduced
// through LDS so only one atomic set per block (4x fewer global atomics).
__global__ void __launch_bounds__(256, 8) kern_bits5(
    const u32* __restrict__ thr9,
    const int* __restrict__ seedp,
    u32* __restrict__ cmp32,        // [bf][t][8]
    u32* __restrict__ occ32) {      // [t][8] OR-reduced over bf
  __shared__ u32 s_red[4][T_PAIR][8];
  const int t0 = blockIdx.x * T_PAIR;
  const int g = blockIdx.y;        // 0..127 (16 bf each)
  const int tid = threadIdx.x;
  const int hoct = tid & 15;       // 16 neurons per thread
  const int bfl = tid >> 4;        // 0..15
  const int bf = g * 16 + bfl;
  const int wid = tid >> 6;
  const u32 seed = (u32)__builtin_amdgcn_readfirstlane((int)seedp[0]);

  const u32 base_i = (u32)(bf * 256 + hoct * 16);

  // 16 pre-shifted thresholds resident in VGPRs (reused for both t-steps)
  u32 th[16];
  const uint4* tp = (const uint4*)(thr9 + base_i);
#pragma unroll
  for (int q = 0; q < 4; ++q) {
    uint4 v = tp[q];
    th[4*q] = v.x; th[4*q+1] = v.y; th[4*q+2] = v.z; th[4*q+3] = v.w;
  }

#pragma unroll 1
  for (int tt = 0; tt < T_PAIR; ++tt) {
    const int t = t0 + tt;
    // k_t = fold_in(key(seed), t) = threefry2x32(key=(0,seed), x=(0,t))
    u32 K0 = 0u, K1 = (u32)t;
    tf2x32(0u, seed, K0, K1);
    const u32 K2 = K0 ^ K1 ^ 0x1BD11BDAu;
    const u32 I10 = K1;
    const u32 I11 = K2 + 1u;
    const u32 I20 = K2;
    const u32 I21 = K0 + 2u;
    const u32 I30 = K0;
    const u32 I31 = K1 + 3u;
    const u32 I40 = K1;
    const u32 I41 = K2 + 4u;
    const u32 I50 = K2;
    const u32 I51 = K0 + 5u;

    const u32 x1base = base_i + K1;     // x1 pre-whitened
    const u32 x0base = x1base + K0;     // x0 after pre-add + first mix add
    u32 wH = 0u, wL = 0u;
#pragma unroll
    for (int j = 7; j >= 0; --j) {
      // chain A: element k = 8+j ; chain B: element k = j (independent)
      u32 a1 = x1base + (u32)(8 + j);
      u32 a0 = x0base + (u32)(8 + j);
      u32 b1 = x1base + (u32)j;
      u32 b0 = x0base + (u32)j;
      a1 = rotl32(a1, 13); a1 ^= a0;    // finish round 1 (both chains)
      b1 = rotl32(b1, 13); b1 ^= b0;
#define QR2(r) { a0 += a1; b0 += b1; \
                 a1 = rotl32(a1, r); b1 = rotl32(b1, r); \
                 a1 ^= a0; b1 ^= b0; }
      QR2(15) QR2(26) QR2(6)
      a0 += I10; b0 += I10; a1 += I11; b1 += I11;
      QR2(17) QR2(29) QR2(16) QR2(24)
      a0 += I20; b0 += I20; a1 += I21; b1 += I21;
      QR2(13) QR2(15) QR2(26) QR2(6)
      a0 += I30; b0 += I30; a1 += I31; b1 += I31;
      QR2(17) QR2(29) QR2(16) QR2(24)
      a0 += I40; b0 += I40; a1 += I41; b1 += I41;
      QR2(13) QR2(15) QR2(26) QR2(6)
      a0 += I50; b0 += I50; a1 += I51; b1 += I51;
#undef QR2
      wH = (wH << 1) | ((a0 ^ a1) < th[8 + j] ? 1u : 0u);
      wL = (wL << 1) | ((b0 ^ b1) < th[j] ? 1u : 0u);
    }
    const u32 word = (wH << 8) | wL;    // bit k of word = element k (exact)

    // merge 16-bit halves into full 32-neuron words (even hoct = low half)
    u32 partner = (u32)__shfl_xor((int)word, 1, 64);
    if (!(hoct & 1)) {
      cmp32[(u32)bf * (T_STEPS * 8) + (u32)t * 8 + (hoct >> 1)] =
          word | (partner << 16);
    }

    // OR across the 4 bf in this wave (lane bits 4..5), then merge halves
    u32 o = word;
    o |= (u32)__shfl_xor((int)o, 16, 64);
    o |= (u32)__shfl_xor((int)o, 32, 64);
    u32 op = (u32)__shfl_xor((int)o, 1, 64);
    if ((tid & 63) < 16 && !(hoct & 1)) {
      s_red[wid][tt][hoct >> 1] = o | (op << 16);
    }
  }
  __syncthreads();
  // one atomic set per block: 16 dwords (2 t x 8 oct-pairs)
  if (tid < T_PAIR * 8) {
    int tt = tid >> 3, op = tid & 7;
    u32 v = s_red[0][tt][op] | s_red[1][tt][op] |
            s_red[2][tt][op] | s_red[3][tt][op];
    atomicOr(&occ32[(t0 + tt) * 8 + op], v);
  }
}

// Stage B+C fused: per-bf block stages cmp into registers, runs the 100-step
// refractory recurrence from occ in LDS, ANDs cmp with can into a TRANSPOSED
// [w][t] LDS layout so the expansion uses conflict-free ds_read_b128,
// then writes float4 output with nontemporal stores.
__global__ void __launch_bounds__(256) kern_out3(
    const u32* __restrict__ cmp32,   // [bf][t][8]
    const u32* __restrict__ occ32,   // [t][8]
    const float* __restrict__ ref0,
    float* __restrict__ out) {
  __shared__ u32 s_occ[T_STEPS * 8];
  __shared__ u32 s_can[T_STEPS * 8];
  __shared__ u32 s[8 * T_STEPS];     // [w][t] transposed
  const int bf = blockIdx.x;
  const int tid = threadIdx.x;

  // stage this bf's cmp slice (3200 B) into registers, coalesced uint4
  uint4 myc = make_uint4(0u, 0u, 0u, 0u);
  if (tid < 200) {
    myc = ((const uint4*)(cmp32 + (u64)bf * (T_STEPS * 8)))[tid];
    ((uint4*)s_occ)[tid] = ((const uint4*)occ32)[tid];
  }
  __syncthreads();

  {
    const int n = tid, lane = n & 63, v = n >> 6;
    float ref = ref0[n];
    for (int t = 0; t < T_STEPS; ++t) {
      bool can = (ref == 0.0f);
      u64 cm = __ballot(can);
      if (lane == 0) {
        s_can[t * 8 + v * 2]     = (u32)cm;
        s_can[t * 8 + v * 2 + 1] = (u32)(cm >> 32);
      }
      bool occb = (s_occ[t * 8 + (n >> 5)] >> (n & 31)) & 1u;
      bool occurred = can && occb;
      ref = fmaxf(ref - 1.0f, 0.0f) + (occurred ? 2.0f : 0.0f);
    }
  }
  __syncthreads();

  // AND + transpose into s[w*100 + t]
  if (tid < 200) {
    const int t = tid >> 1, w0 = (tid & 1) * 4;
    const u32* mp = (const u32*)&myc;
#pragma unroll
    for (int j = 0; j < 4; ++j) {
      s[(w0 + j) * T_STEPS + t] = mp[j] & s_can[t * 8 + w0 + j];
    }
  }
  __syncthreads();

  f32x4* outv = (f32x4*)(out + (u64)bf * (NNEUR * T_STEPS));
#pragma unroll
  for (int kk = 0; kk < 25; ++kk) {
    int q = tid + 256 * kk;          // float4 index within slice (6400 total)
    int e = q * 4;
    int n = e / 100;
    int t0 = e - n * 100;            // multiple of 4 (100 % 4 == 0)
    int bit = n & 31;
    uint4 wv = *(const uint4*)&s[(n >> 5) * T_STEPS + t0];  // ds_read_b128
    f32x4 val;
    val[0] = (float)((wv.x >> bit) & 1u);
    val[1] = (float)((wv.y >> bit) & 1u);
    val[2] = (float)((wv.z >> bit) & 1u);
    val[3] = (float)((wv.w >> bit) & 1u);
    __builtin_nontemporal_store(val, &outv[q]);
  }
}

// ---------------- fallback path (ws too small): round-1 working scheme ----
__global__ void __launch_bounds__(256) kern_bits_fb(
    const float* __restrict__ x, const float* __restrict__ c,
    const float* __restrict__ w, const float* __restrict__ a,
    const int* __restrict__ seedp,
    float* __restrict__ outf,
    u64* __restrict__ occ64) {
  const int t = blockIdx.x;
  const int chunk = blockIdx.y;
  const int lane = threadIdx.x & 63;
  const int v = threadIdx.x >> 6;
  const int n = v * 64 + lane;
  const u32 seed = (u32)seedp[0];
  u32 kt0 = 0u, kt1 = (u32)t;
  tf2x32(0u, seed, kt0, kt1);
  float cn = c[n], wn = w[n], an = a[n];
  bool occ = false;
  for (int j = 0; j < 64; ++j) {
    int bf = chunk * 64 + j;
    u32 i = (u32)(bf * 256 + n);
    u32 b0 = 0u, b1 = i;
    tf2x32(kt0, kt1, b0, b1);
    u32 bits = b0 ^ b1;
    float r = __uint_as_float((bits >> 9) | 0x3F800000u) - 1.0f;
    float d = x[bf] - cn;
    float denom = (2.0f * wn) * wn;
    float q = -(d * d) / denom;
    float pv = ((float)exp((double)q) * an) * 0.1f;
    bool cm = r < pv;
    occ |= cm;
    outf[(u64)bf * (NNEUR * T_STEPS) + (u64)n * T_STEPS + t] = cm ? 1.0f : 0.0f;
  }
  u64 om = __ballot(occ);
  if (lane == 0) atomicOr(&occ64[t * 4 + v], om);
}

__global__ void __launch_bounds__(256) kern_rec(
    const float* __restrict__ ref0,
    const u64* __restrict__ occ64,
    u64* __restrict__ can64) {
  int n = threadIdx.x;
  int lane = n & 63, v = n >> 6;
  float ref = ref0[n];
  for (int t = 0; t < T_STEPS; ++t) {
    bool can = (ref == 0.0f);
    u64 cm = __ballot(can);
    if (lane == 0) can64[t * 4 + v] = cm;
    bool occb = (occ64[t * 4 + v] >> lane) & 1ull;
    bool occurred = can && occb;
    ref = fmaxf(ref - 1.0f, 0.0f) + (occurred ? 2.0f : 0.0f);
  }
}

__global__ void __launch_bounds__(256) kern_mask(
    const u32* __restrict__ can32, float* __restrict__ out) {
  u64 q = (u64)blockIdx.x * 256 + threadIdx.x;
  float4* ov = (float4*)out;
  float4 vx = ov[q];
  u32 local = (u32)((q * 4) % (NNEUR * T_STEPS));
  float* vp = (float*)&vx;
#pragma unroll
  for (int j = 0; j < 4; ++j) {
    u32 le = local + j;
    u32 n = le / 100;
    u32 t = le - n * 100;
    u32 bit = (can32[t * 8 + (n >> 5)] >> (n & 31)) & 1u;
    vp[j] = bit ? vp[j] : 0.0f;
  }
  ov[q] = vx;
}

extern "C" void kernel_launch(void* const* d_in, const int* in_sizes, int n_in,
                              void* d_out, int out_size, void* d_ws, size_t ws_size,
                              hipStream_t stream) {
  const float* x  = (const float*)d_in[0];
  const float* c  = (const float*)d_in[1];
  const float* w  = (const float*)d_in[2];
  const float* a  = (const float*)d_in[3];
  const float* r0 = (const float*)d_in[4];
  const int* seed = (const int*)d_in[5];
  float* out = (float*)d_out;

  const size_t P_BYTES   = (size_t)NELEM * 4;                    // 2 MB thresholds
  const size_t CMP_BYTES = (size_t)NBF * T_STEPS * 4 * 8;        // 6.55 MB
  const size_t OCC_BYTES = (size_t)T_STEPS * 4 * 8;              // 3200 B
  const bool full = ws_size >= P_BYTES + CMP_BYTES + 2 * OCC_BYTES;

  uint8_t* wsb = (uint8_t*)d_ws;

  if (full) {
    u32* thr   = (u32*)wsb;
    u32* cmp   = (u32*)(wsb + P_BYTES);
    u32* occ   = (u32*)(wsb + P_BYTES + CMP_BYTES);
    kern_p<<<NELEM / 256, 256, 0, stream>>>(x, c, w, a, thr, occ);
    kern_bits5<<<dim3(T_STEPS / T_PAIR, 128), 256, 0, stream>>>(thr, seed, cmp, occ);
    kern_out3<<<NBF, 256, 0, stream>>>(cmp, occ, r0, out);
  } else {
    u64* occ = (u64*)wsb;
    u64* can = (u64*)(wsb + OCC_BYTES);
    hipMemsetAsync(occ, 0, OCC_BYTES, stream);
    kern_bits_fb<<<dim3(T_STEPS, 32), 256, 0, stream>>>(x, c, w, a, seed, out, occ);
    kern_rec<<<1, 256, 0, stream>>>(r0, occ, can);
    kern_mask<<<(out_size / 4) / 256, 256, 0, stream>>>((const u32*)can, out);
  }
}